// Round 17
// baseline (236.464 us; speedup 1.0000x reference)
//
#include <hip/hip_runtime.h>

#define EMB 64
#define NBMAX 512      // max buckets (NB = ceil(N/512) = 293 for N=150000)
#define BCAP 8192      // bucket edge capacity (mean 6827, +16 sigma; = 16*512)
#define BSTRIDE 12288  // padded bucket region: BCAP + 512 nodes * 8 pad slots
#define CHUNK 4096     // edges per partition WG

// ---------------- bf16 helpers ----------------

__device__ __forceinline__ unsigned short f2bf(float f) {   // round-to-nearest-even
    union { float f; unsigned u; } c; c.f = f;
    unsigned r = c.u + 0x7fffu + ((c.u >> 16) & 1u);
    return (unsigned short)(r >> 16);
}
__device__ __forceinline__ float bflo(unsigned u) {         // low bf16 -> f32
    union { unsigned u; float f; } c; c.u = u << 16; return c.f;
}
__device__ __forceinline__ float bfhi(unsigned u) {         // high bf16 -> f32
    union { unsigned u; float f; } c; c.u = u & 0xffff0000u; return c.f;
}
__device__ __forceinline__ unsigned pack2(float a, float b) {
    return (unsigned)f2bf(a) | ((unsigned)f2bf(b) << 16);
}

// ================= init: zero bcursor + phantom rows =================

__global__ void init_kernel(unsigned* __restrict__ p, int nz,
                            unsigned* __restrict__ dummyA,
                            unsigned* __restrict__ dummyB) {
    int i = blockIdx.x * blockDim.x + threadIdx.x;
    if (i < nz) p[i] = 0u;
    if (blockIdx.x == 0) {
        int t = threadIdx.x;
        if (t < 32) dummyA[t] = 0u;
        else if (t < 64) dummyB[t - 32] = 0u;
    }
}

// ================= weight prep: transpose to [k][64] + fused biases =========
// wbuf layout (floats): uWnT[12*64] @0 | uWvT[3*64] @768 | iWnT[5*64] @960 |
//                       iWvT[12*64] @1280 | ubnv[64] @2048 | ibnv[64] @2112

__global__ void prep_weights_kernel(const float* __restrict__ uWn,
                                    const float* __restrict__ ubn,
                                    const float* __restrict__ uWv,
                                    const float* __restrict__ ubv,
                                    const float* __restrict__ iWn,
                                    const float* __restrict__ ibn,
                                    const float* __restrict__ iWv,
                                    const float* __restrict__ ibv,
                                    float* __restrict__ wbuf) {
    int t = blockIdx.x * blockDim.x + threadIdx.x;
    if (t < 768)       { int r = t;        wbuf[t] = uWn[(r & 63) * 12 + (r >> 6)]; }
    else if (t < 960)  { int r = t - 768;  wbuf[t] = uWv[(r & 63) * 3  + (r >> 6)]; }
    else if (t < 1280) { int r = t - 960;  wbuf[t] = iWn[(r & 63) * 5  + (r >> 6)]; }
    else if (t < 2048) { int r = t - 1280; wbuf[t] = iWv[(r & 63) * 12 + (r >> 6)]; }
    else if (t < 2112) { int d = t - 2048; wbuf[t] = ubn[d] + ubv[d]; }
    else if (t < 2176) { int d = t - 2112; wbuf[t] = ibn[d] + ibv[d]; }
}

// ================= feature fusion (coalesced weights, shfl features) ========
// 32 threads/node, 2 dims/thread. Weight loads are float2 from transposed
// wbuf (consecutive lanes -> consecutive addresses). Features loaded once
// (lane m<nf) and broadcast via __shfl within the 32-lane group.

__global__ __launch_bounds__(256) void fuse_kernel(
        const float* __restrict__ ufeat,      // [U,15]
        const int* __restrict__ cidx, const int* __restrict__ sidx,
        const float* __restrict__ uemb,       // [U,64]
        const float* __restrict__ color_w,    // [22,64]
        const float* __restrict__ size_w,     // [18,64]
        const float* __restrict__ ifeat,      // [I,17]
        const float* __restrict__ iemb,       // [I,64]
        const float* __restrict__ wbuf,       // transposed weights (see above)
        const float* __restrict__ dis,        // [N]
        unsigned* __restrict__ totB,          // [N*32] bf16x2
        unsigned* __restrict__ y0,            // [(N+1)*32] bf16x2
        int U, int N) {
    int t = blockIdx.x * blockDim.x + threadIdx.x;
    int n = t >> 5, m = t & 31;
    if (n >= N) return;
    const float2* uWnT = (const float2*)(wbuf);
    const float2* uWvT = (const float2*)(wbuf + 768);
    const float2* iWnT = (const float2*)(wbuf + 960);
    const float2* iWvT = (const float2*)(wbuf + 1280);
    const float2* ubnv = (const float2*)(wbuf + 2048);
    const float2* ibnv = (const float2*)(wbuf + 2112);
    bool isU = n < U;
    const float* fb = isU ? &ufeat[(size_t)n * 15] : &ifeat[(size_t)(n - U) * 17];
    int nf = isU ? 15 : 17;
    float fown = (m < nf) ? fb[m] : 0.f;   // one load/lane, then shfl-broadcast
    float acc0, acc1;
    if (isU) {
        float2 e = *reinterpret_cast<const float2*>(&uemb[(size_t)n * EMB + 2 * m]);
        float2 bb = ubnv[m];
        acc0 = e.x + bb.x; acc1 = e.y + bb.y;
#pragma unroll
        for (int k = 0; k < 12; ++k) {
            float fv = __shfl(fown, k, 32);
            float2 w = uWnT[k * 32 + m];
            acc0 = fmaf(fv, w.x, acc0); acc1 = fmaf(fv, w.y, acc1);
        }
#pragma unroll
        for (int k = 0; k < 3; ++k) {
            float fv = __shfl(fown, 12 + k, 32);
            float2 w = uWvT[k * 32 + m];
            acc0 = fmaf(fv, w.x, acc0); acc1 = fmaf(fv, w.y, acc1);
        }
        float2 cw = *reinterpret_cast<const float2*>(&color_w[(size_t)cidx[n] * EMB + 2 * m]);
        float2 sw = *reinterpret_cast<const float2*>(&size_w[(size_t)sidx[n] * EMB + 2 * m]);
        acc0 += cw.x + sw.x;
        acc1 += cw.y + sw.y;
    } else {
        int i = n - U;
        float2 e = *reinterpret_cast<const float2*>(&iemb[(size_t)i * EMB + 2 * m]);
        float2 bb = ibnv[m];
        acc0 = e.x + bb.x; acc1 = e.y + bb.y;
#pragma unroll
        for (int k = 0; k < 5; ++k) {
            float fv = __shfl(fown, k, 32);
            float2 w = iWnT[k * 32 + m];
            acc0 = fmaf(fv, w.x, acc0); acc1 = fmaf(fv, w.y, acc1);
        }
#pragma unroll
        for (int k = 0; k < 12; ++k) {
            float fv = __shfl(fown, 5 + k, 32);
            float2 w = iWvT[k * 32 + m];
            acc0 = fmaf(fv, w.x, acc0); acc1 = fmaf(fv, w.y, acc1);
        }
    }
    float dv = dis[n];
    size_t o = (size_t)n * 32 + m;
    totB[o] = pack2(acc0, acc1);
    y0[o] = pack2(acc0 * dv, acc1 * dv);
}

// ================= bucketed CSR build =================
// pass 1: partition edges into NB col-range buckets (packed row<<9 | col&511)
// cols register-cached between histogram and scatter phases.

__global__ __launch_bounds__(512) void partition_kernel(
        const int* __restrict__ row, const int* __restrict__ col,
        unsigned* __restrict__ bcursor, unsigned* __restrict__ bucketbuf,
        int E, int NB) {
    __shared__ unsigned h[NBMAX];
    __shared__ unsigned wbase[NBMAX];
    const int t = threadIdx.x;
    const long chunk = (long)blockIdx.x * CHUNK;

    for (int i = t; i < NB; i += 512) h[i] = 0u;
    __syncthreads();
    unsigned cc[2][4];
#pragma unroll
    for (int it = 0; it < 2; ++it) {
        long e = chunk + (long)it * 2048 + (long)t * 4;
        if (e + 3 < (long)E) {
            uint4 c4 = *reinterpret_cast<const uint4*>(&col[e]);
            cc[it][0] = c4.x; cc[it][1] = c4.y; cc[it][2] = c4.z; cc[it][3] = c4.w;
            atomicAdd(&h[c4.x >> 9], 1u); atomicAdd(&h[c4.y >> 9], 1u);
            atomicAdd(&h[c4.z >> 9], 1u); atomicAdd(&h[c4.w >> 9], 1u);
        } else {
#pragma unroll
            for (int k = 0; k < 4; ++k) {
                long ek = e + k;
                unsigned cv = (ek < (long)E) ? (unsigned)col[ek] : 0xffffffffu;
                cc[it][k] = cv;
                if (cv != 0xffffffffu) atomicAdd(&h[cv >> 9], 1u);
            }
        }
    }
    __syncthreads();
    for (int i = t; i < NB; i += 512) {
        unsigned c = h[i];
        wbase[i] = c ? atomicAdd(&bcursor[i], c) : 0u;
    }
    __syncthreads();
    for (int i = t; i < NB; i += 512) h[i] = 0u;
    __syncthreads();
#pragma unroll
    for (int it = 0; it < 2; ++it) {
        long e = chunk + (long)it * 2048 + (long)t * 4;
        if (e + 3 < (long)E) {
            uint4 r4 = *reinterpret_cast<const uint4*>(&row[e]);
            unsigned rs[4] = {r4.x, r4.y, r4.z, r4.w};
#pragma unroll
            for (int k = 0; k < 4; ++k) {
                unsigned cv = cc[it][k];
                unsigned b = cv >> 9;
                unsigned pos = wbase[b] + atomicAdd(&h[b], 1u);
                if (pos < BCAP)
                    bucketbuf[(size_t)b * BCAP + pos] = (rs[k] << 9) | (cv & 511u);
            }
        } else {
#pragma unroll
            for (int k = 0; k < 4; ++k) {
                long ek = e + k;
                unsigned cv = cc[it][k];
                if (cv != 0xffffffffu) {
                    unsigned b = cv >> 9;
                    unsigned pos = wbase[b] + atomicAdd(&h[b], 1u);
                    if (pos < BCAP)
                        bucketbuf[(size_t)b * BCAP + pos] =
                            (((unsigned)row[ek]) << 9) | (cv & 511u);
                }
            }
        }
    }
}

// pass 2: one 512-thread WG per bucket (1 node/thread). Packed edges are
// register-cached (cntb <= 16*512) across histogram->scatter. Produces meta
// (pad-8), dis, srcidx (pre-shifted + phantom pads), and longest-first
// in-bucket degree-sorted order[].

__global__ __launch_bounds__(512) void bucket_csr_kernel(
        const unsigned* __restrict__ bcursor,
        const unsigned* __restrict__ bucketbuf,
        uint4* __restrict__ meta,               // [N] {beg,end,dis_bits,0}
        float* __restrict__ dis, unsigned* __restrict__ srcidx,
        unsigned* __restrict__ order,           // [N] degree-sorted ids
        int N, int NB) {
    const int b = blockIdx.x;
    const int t = threadIdx.x;
    __shared__ unsigned hist[512];
    __shared__ unsigned ps[512];
    __shared__ unsigned cls[64];
    __shared__ unsigned clsB[64];

    const unsigned base = (unsigned)b * BSTRIDE;
    unsigned cntb = bcursor[b];
    if (cntb > BCAP) cntb = BCAP;

    hist[t] = 0u;
    if (t < 64) cls[t] = 0u;
    __syncthreads();
    const unsigned* buf = bucketbuf + (size_t)b * BCAP;
    unsigned rv[16];
#pragma unroll
    for (int it = 0; it < 16; ++it) {
        unsigned j = (unsigned)t + (unsigned)it * 512u;
        unsigned p = (j < cntb) ? buf[j] : 0xffffffffu;
        rv[it] = p;
        if (p != 0xffffffffu) atomicAdd(&hist[p & 511u], 1u);
    }
    __syncthreads();

    unsigned h0 = hist[t];
    unsigned c0p = (h0 + 7u) & ~7u;    // pad to multiple of 8
    ps[t] = c0p;
    __syncthreads();
    for (int off = 1; off < 512; off <<= 1) {
        unsigned y = (t >= off) ? ps[t - off] : 0u;
        __syncthreads();
        ps[t] += y;
        __syncthreads();
    }
    unsigned beg0 = base + ps[t] - c0p;

    int n0 = (b << 9) + t;
    unsigned c = 63u - min(c0p >> 3, 63u);   // inverted: longest-first
    unsigned lpos = 0;
    if (n0 < N) {
        float dv = h0 ? rsqrtf((float)h0) : 0.f;
        meta[n0] = make_uint4(beg0, beg0 + c0p, __float_as_uint(dv), 0u);
        dis[n0] = dv;
        lpos = atomicAdd(&cls[c], 1u);       // rank within class
        for (unsigned k = h0; k < c0p; ++k) srcidx[beg0 + k] = ((unsigned)N) << 5;
    }
    __syncthreads();
    if (t == 0) {   // exclusive scan of the 64 class counts
        unsigned run = 0;
        for (int i = 0; i < 64; ++i) { unsigned v = cls[i]; clsB[i] = run; run += v; }
    }
    __syncthreads();
    if (n0 < N) order[(b << 9) + clsB[c] + lpos] = (unsigned)n0;

    // scatter from registers via LDS cursors; writes stay in one bucket region
    hist[t] = beg0;
    __syncthreads();
#pragma unroll
    for (int it = 0; it < 16; ++it) {
        unsigned p = rv[it];
        if (p != 0xffffffffu) {
            unsigned pos = atomicAdd(&hist[p & 511u], 1u);
            srcidx[pos] = (p >> 9) << 5;   // u32 word offset of source row
        }
    }
}

// ================= propagation =================
// TWO nodes per wave (degree-sorted, longest-first), 16-edge unrolled main
// loop with two accumulator banks + one 8-edge tail (lists pad-8). totB read
// hoisted. mode 0: RMW bf16 totB + store ynext; mode 1: f32 out*(0.25) fused.

__global__ __launch_bounds__(256) void gather_propagate_kernel(
        const unsigned* __restrict__ order, const uint4* __restrict__ meta,
        const unsigned* __restrict__ src,   // [(N+1)*32]
        const unsigned* __restrict__ srcidx,
        unsigned* __restrict__ ynext,       // [(N+1)*32]
        unsigned* __restrict__ totB,        // [N*32] bf16x2
        float4* __restrict__ outF,          // [N*16] f32 (mode 1)
        int N, int mode) {
    int lane = threadIdx.x & 63;
    int slot = blockIdx.x * 8 + ((threadIdx.x >> 6) << 1) + (lane >> 5);
    bool active = slot < N;
    int n = active ? (int)order[slot] : 0;
    uint4 md = active ? meta[n] : make_uint4(0u, 0u, 0u, 0u);
    unsigned beg = md.x, endp = md.y;
    float dn = __uint_as_float(md.z);
    unsigned q = (unsigned)((lane >> 4) & 1);
    unsigned m2 = (unsigned)(lane & 15) * 2u;
    size_t o = (size_t)n * 32 + m2;
    uint2 tv = *reinterpret_cast<const uint2*>(&totB[o]);   // hoisted RMW-read
    float s0 = 0.f, s1 = 0.f, s2 = 0.f, s3 = 0.f;
    float t0 = 0.f, t1 = 0.f, t2 = 0.f, t3 = 0.f;
    unsigned j = beg;
    for (; j + 16 <= endp; j += 16) {   // 16 edges/node/iter, 2 chains
        uint4 iv0 = *reinterpret_cast<const uint4*>(&srcidx[j + 4u * q]);
        uint4 iv1 = *reinterpret_cast<const uint4*>(&srcidx[j + 8u + 4u * q]);
        uint2 ua = *reinterpret_cast<const uint2*>(&src[iv0.x + m2]);
        uint2 ub = *reinterpret_cast<const uint2*>(&src[iv0.y + m2]);
        uint2 uc = *reinterpret_cast<const uint2*>(&src[iv0.z + m2]);
        uint2 ud = *reinterpret_cast<const uint2*>(&src[iv0.w + m2]);
        uint2 ue = *reinterpret_cast<const uint2*>(&src[iv1.x + m2]);
        uint2 uf = *reinterpret_cast<const uint2*>(&src[iv1.y + m2]);
        uint2 ug = *reinterpret_cast<const uint2*>(&src[iv1.z + m2]);
        uint2 uh = *reinterpret_cast<const uint2*>(&src[iv1.w + m2]);
        s0 += (bflo(ua.x) + bflo(ub.x)) + (bflo(uc.x) + bflo(ud.x));
        s1 += (bfhi(ua.x) + bfhi(ub.x)) + (bfhi(uc.x) + bfhi(ud.x));
        s2 += (bflo(ua.y) + bflo(ub.y)) + (bflo(uc.y) + bflo(ud.y));
        s3 += (bfhi(ua.y) + bfhi(ub.y)) + (bfhi(uc.y) + bfhi(ud.y));
        t0 += (bflo(ue.x) + bflo(uf.x)) + (bflo(ug.x) + bflo(uh.x));
        t1 += (bfhi(ue.x) + bfhi(uf.x)) + (bfhi(ug.x) + bfhi(uh.x));
        t2 += (bflo(ue.y) + bflo(uf.y)) + (bflo(ug.y) + bflo(uh.y));
        t3 += (bfhi(ue.y) + bfhi(uf.y)) + (bfhi(ug.y) + bfhi(uh.y));
    }
    if (j < endp) {   // exactly one 8-edge tail (pad-8 lists)
        uint4 iv = *reinterpret_cast<const uint4*>(&srcidx[j + 4u * q]);
        uint2 ua = *reinterpret_cast<const uint2*>(&src[iv.x + m2]);
        uint2 ub = *reinterpret_cast<const uint2*>(&src[iv.y + m2]);
        uint2 uc = *reinterpret_cast<const uint2*>(&src[iv.z + m2]);
        uint2 ud = *reinterpret_cast<const uint2*>(&src[iv.w + m2]);
        s0 += (bflo(ua.x) + bflo(ub.x)) + (bflo(uc.x) + bflo(ud.x));
        s1 += (bfhi(ua.x) + bfhi(ub.x)) + (bfhi(uc.x) + bfhi(ud.x));
        s2 += (bflo(ua.y) + bflo(ub.y)) + (bflo(uc.y) + bflo(ud.y));
        s3 += (bfhi(ua.y) + bfhi(ub.y)) + (bfhi(uc.y) + bfhi(ud.y));
    }
    s0 += t0; s1 += t1; s2 += t2; s3 += t3;
    // combine the two q-groups within each half (xor 16 stays inside the half)
    s0 += __shfl_xor(s0, 16);
    s1 += __shfl_xor(s1, 16);
    s2 += __shfl_xor(s2, 16);
    s3 += __shfl_xor(s3, 16);
    if (active && (lane & 31) < 16) {
        float a0 = dn * s0, a1 = dn * s1, a2 = dn * s2, a3 = dn * s3;
        float b0 = bflo(tv.x) + a0, b1 = bfhi(tv.x) + a1;
        float b2 = bflo(tv.y) + a2, b3 = bfhi(tv.y) + a3;
        if (mode == 0) {
            uint2 nv;
            nv.x = pack2(b0, b1);
            nv.y = pack2(b2, b3);
            *reinterpret_cast<uint2*>(&totB[o]) = nv;
            uint2 pk;
            pk.x = pack2(dn * a0, dn * a1);
            pk.y = pack2(dn * a2, dn * a3);
            *reinterpret_cast<uint2*>(&ynext[(size_t)n * 32 + m2]) = pk;
        } else {
            outF[(size_t)n * 16 + (m2 >> 1)] =
                make_float4(b0 * 0.25f, b1 * 0.25f, b2 * 0.25f, b3 * 0.25f);
        }
    }
}

// ================= launch =================

extern "C" void kernel_launch(void* const* d_in, const int* in_sizes, int n_in,
                              void* d_out, int out_size, void* d_ws, size_t ws_size,
                              hipStream_t stream) {
    const int*   edge       = (const int*)d_in[0];
    const float* user_feat  = (const float*)d_in[1];
    const int*   cidx       = (const int*)d_in[2];
    const int*   sidx       = (const int*)d_in[3];
    const float* item_feat  = (const float*)d_in[4];
    const float* user_emb_w = (const float*)d_in[5];
    const float* item_emb_w = (const float*)d_in[6];
    const float* uWn        = (const float*)d_in[7];
    const float* ubn        = (const float*)d_in[8];
    const float* uWv        = (const float*)d_in[9];
    const float* ubv        = (const float*)d_in[10];
    const float* color_w    = (const float*)d_in[11];
    const float* size_w     = (const float*)d_in[12];
    const float* iWn        = (const float*)d_in[13];
    const float* ibn        = (const float*)d_in[14];
    const float* iWv        = (const float*)d_in[15];
    const float* ibv        = (const float*)d_in[16];

    const int E = in_sizes[0] / 2;
    const int U = in_sizes[5] / EMB;
    const int I = in_sizes[6] / EMB;
    const int N = U + I;
    const int NB = (N + 511) >> 9;     // 293 buckets

    const int* row = edge;
    const int* col = edge + E;

    // workspace layout (u32 units)
    unsigned short* yA      = (unsigned short*)d_ws;          // [(N+1)*64] bf16
    unsigned short* yB      = yA + (size_t)(N + 1) * EMB;     // [(N+1)*64] bf16
    unsigned*       bucketbuf = (unsigned*)yB;                // [NB*BCAP] aliases yB
                                                              // (dummy row at word
                                                              // N*32=4.8M > 2.4M cap
                                                              // -> no overlap)
    unsigned short* totB    = yB + (size_t)(N + 1) * EMB;     // [N*64] bf16 running sum
    unsigned*       srcidx  = (unsigned*)(totB + (size_t)N * EMB);      // [NB*BSTRIDE]
    uint4*          meta    = (uint4*)(srcidx + (size_t)NB * BSTRIDE);  // [N]
    float*          dis     = (float*)(meta + N);             // [N]
    unsigned*       bcursor = (unsigned*)(dis + N);           // [NB]
    unsigned*       order   = bcursor + ((NB + 1) & ~1);      // [N] (8B-aligned)
    float*          wbuf    = (float*)(order + ((N + 1) & ~1)); // [2176] (8B-aligned)

    const int TB = 256;

    // 1. init (bcursor + phantom rows) + weight transpose, then CSR build
    init_kernel<<<(NB + TB - 1) / TB, TB, 0, stream>>>(
        bcursor, NB,
        (unsigned*)(yA + (size_t)N * EMB), (unsigned*)(yB + (size_t)N * EMB));
    prep_weights_kernel<<<(2176 + TB - 1) / TB, TB, 0, stream>>>(
        uWn, ubn, uWv, ubv, iWn, ibn, iWv, ibv, wbuf);
    const int gP = (E + CHUNK - 1) / CHUNK;
    partition_kernel<<<gP, 512, 0, stream>>>(row, col, bcursor, bucketbuf, E, NB);
    bucket_csr_kernel<<<NB, 512, 0, stream>>>(bcursor, bucketbuf, meta, dis,
                                              srcidx, order, N, NB);

    // 2. fuse features: totB = bf16(x), yA = bf16(dis*x)
    {
        long tF = (long)N * 32;
        fuse_kernel<<<(int)((tF + TB - 1) / TB), TB, 0, stream>>>(
            user_feat, cidx, sidx, user_emb_w, color_w, size_w,
            item_feat, item_emb_w, wbuf, dis,
            (unsigned*)totB, (unsigned*)yA, U, N);
    }

    // 3. three propagation layers; finalize fused into layer 3 (mode 1)
    const int gG = (N + 7) / 8;   // 8 degree-matched nodes per block (2/wave)
    gather_propagate_kernel<<<gG, TB, 0, stream>>>(order, meta,
                                                   (const unsigned*)yA, srcidx,
                                                   (unsigned*)yB, (unsigned*)totB,
                                                   (float4*)d_out, N, 0);
    gather_propagate_kernel<<<gG, TB, 0, stream>>>(order, meta,
                                                   (const unsigned*)yB, srcidx,
                                                   (unsigned*)yA, (unsigned*)totB,
                                                   (float4*)d_out, N, 0);
    gather_propagate_kernel<<<gG, TB, 0, stream>>>(order, meta,
                                                   (const unsigned*)yA, srcidx,
                                                   (unsigned*)yB, (unsigned*)totB,
                                                   (float4*)d_out, N, 1);

    (void)n_in; (void)out_size; (void)ws_size;
}

// Round 18
// 227.716 us; speedup vs baseline: 1.0384x; 1.0384x over previous
//
#include <hip/hip_runtime.h>

#define EMB 64
#define NBMAX 512      // max buckets (NB = ceil(N/512) = 293 for N=150000)
#define BCAP 8192      // bucket edge capacity (mean 6827, +16 sigma; = 16*512)
#define BSTRIDE 12288  // padded bucket region: BCAP + 512 nodes * 8 pad slots
#define CHUNK 4096     // edges per partition WG
#define WSZ 2304       // wbuf floats: uW17[1088] | iW17[1088] | ubnv[64] | ibnv[64]

// ---------------- bf16 helpers ----------------

__device__ __forceinline__ unsigned short f2bf(float f) {   // round-to-nearest-even
    union { float f; unsigned u; } c; c.f = f;
    unsigned r = c.u + 0x7fffu + ((c.u >> 16) & 1u);
    return (unsigned short)(r >> 16);
}
__device__ __forceinline__ float bflo(unsigned u) {         // low bf16 -> f32
    union { unsigned u; float f; } c; c.u = u << 16; return c.f;
}
__device__ __forceinline__ float bfhi(unsigned u) {         // high bf16 -> f32
    union { unsigned u; float f; } c; c.u = u & 0xffff0000u; return c.f;
}
__device__ __forceinline__ unsigned pack2(float a, float b) {
    return (unsigned)f2bf(a) | ((unsigned)f2bf(b) << 16);
}

// ================= init: zero bcursor + phantom rows =================

__global__ void init_kernel(unsigned* __restrict__ p, int nz,
                            unsigned* __restrict__ dummyA,
                            unsigned* __restrict__ dummyB) {
    int i = blockIdx.x * blockDim.x + threadIdx.x;
    if (i < nz) p[i] = 0u;
    if (blockIdx.x == 0) {
        int t = threadIdx.x;
        if (t < 32) dummyA[t] = 0u;
        else if (t < 64) dummyB[t - 32] = 0u;
    }
}

// ================= weight prep: uniform padded W17[17][64] per type ========
// uW17: k<12 -> uWn col k; k in 12..14 -> uWv col k-12; k 15,16 -> 0
// iW17: k<5  -> iWn col k; k in 5..16  -> iWv col k-5
// + fused bias pairs. Total 2304 floats = 9.2 KB.

__global__ void prep_weights_kernel(const float* __restrict__ uWn,
                                    const float* __restrict__ ubn,
                                    const float* __restrict__ uWv,
                                    const float* __restrict__ ubv,
                                    const float* __restrict__ iWn,
                                    const float* __restrict__ ibn,
                                    const float* __restrict__ iWv,
                                    const float* __restrict__ ibv,
                                    float* __restrict__ wbuf) {
    int t = blockIdx.x * blockDim.x + threadIdx.x;
    if (t < 1088) {
        int k = t >> 6, d = t & 63;
        float v = (k < 12) ? uWn[d * 12 + k] : (k < 15 ? uWv[d * 3 + (k - 12)] : 0.f);
        wbuf[t] = v;
    } else if (t < 2176) {
        int r = t - 1088;
        int k = r >> 6, d = r & 63;
        float v = (k < 5) ? iWn[d * 5 + k] : iWv[d * 12 + (k - 5)];
        wbuf[t] = v;
    } else if (t < 2240) {
        int d = t - 2176; wbuf[t] = ubn[d] + ubv[d];
    } else if (t < WSZ) {
        int d = t - 2240; wbuf[t] = ibn[d] + ibv[d];
    }
}

// ================= feature fusion (LDS weights, 2 nodes/thread) ============
// Block = 256 threads = 8 dim-groups; each thread owns dim-pair m of nodes
// nA = base+l and nB = base+l+8 (16 nodes/block). Weights read from LDS
// (uniform 17-step loop, types differ only in LDS base). Two independent
// accumulator chains give the scheduler ~12 VMEM in flight per thread.

__global__ __launch_bounds__(256, 4) void fuse_kernel(
        const float* __restrict__ ufeat,      // [U,15]
        const int* __restrict__ cidx, const int* __restrict__ sidx,
        const float* __restrict__ uemb,       // [U,64]
        const float* __restrict__ color_w,    // [22,64]
        const float* __restrict__ size_w,     // [18,64]
        const float* __restrict__ ifeat,      // [I,17]
        const float* __restrict__ iemb,       // [I,64]
        const float* __restrict__ wbuf,       // WSZ floats (see prep)
        const float* __restrict__ dis,        // [N]
        unsigned* __restrict__ totB,          // [N*32] bf16x2
        unsigned* __restrict__ y0,            // [(N+1)*32] bf16x2
        int U, int N) {
    __shared__ float lw[WSZ];
    int t = threadIdx.x;
    for (int i = t; i < WSZ; i += 256) lw[i] = wbuf[i];
    __syncthreads();
    int m = t & 31;
    int l = t >> 5;
    int nA = blockIdx.x * 16 + l;
    int nB = nA + 8;
    bool vA = nA < N, vB = nB < N;
    int cA = vA ? nA : 0, cB = vB ? nB : 0;
    bool uA = cA < U, uB = cB < U;
    // feature loads (one per node, shfl-broadcast in the 17-loop)
    const float* fbA = uA ? &ufeat[(size_t)cA * 15] : &ifeat[(size_t)(cA - U) * 17];
    const float* fbB = uB ? &ufeat[(size_t)cB * 15] : &ifeat[(size_t)(cB - U) * 17];
    int nfA = uA ? 15 : 17, nfB = uB ? 15 : 17;
    float fownA = (m < nfA) ? fbA[m] : 0.f;
    float fownB = (m < nfB) ? fbB[m] : 0.f;
    // embeddings
    const float* ebA = uA ? &uemb[(size_t)cA * EMB] : &iemb[(size_t)(cA - U) * EMB];
    const float* ebB = uB ? &uemb[(size_t)cB * EMB] : &iemb[(size_t)(cB - U) * EMB];
    float2 eA = *reinterpret_cast<const float2*>(&ebA[2 * m]);
    float2 eB = *reinterpret_cast<const float2*>(&ebB[2 * m]);
    float dvA = dis[cA], dvB = dis[cB];
    int offA = uA ? 0 : 1088, offB = uB ? 0 : 1088;
    float2 bbA = *reinterpret_cast<const float2*>(&lw[2176 + (uA ? 0 : 64) + 2 * m]);
    float2 bbB = *reinterpret_cast<const float2*>(&lw[2176 + (uB ? 0 : 64) + 2 * m]);
    float a0 = eA.x + bbA.x, a1 = eA.y + bbA.y;
    float b0 = eB.x + bbB.x, b1 = eB.y + bbB.y;
#pragma unroll
    for (int k = 0; k < 17; ++k) {
        float fvA = __shfl(fownA, k, 32);
        float fvB = __shfl(fownB, k, 32);
        float2 wA = *reinterpret_cast<const float2*>(&lw[offA + k * 64 + 2 * m]);
        float2 wB = *reinterpret_cast<const float2*>(&lw[offB + k * 64 + 2 * m]);
        a0 = fmaf(fvA, wA.x, a0); a1 = fmaf(fvA, wA.y, a1);
        b0 = fmaf(fvB, wB.x, b0); b1 = fmaf(fvB, wB.y, b1);
    }
    if (uA) {
        float2 cw = *reinterpret_cast<const float2*>(&color_w[(size_t)cidx[cA] * EMB + 2 * m]);
        float2 sw = *reinterpret_cast<const float2*>(&size_w[(size_t)sidx[cA] * EMB + 2 * m]);
        a0 += cw.x + sw.x; a1 += cw.y + sw.y;
    }
    if (uB) {
        float2 cw = *reinterpret_cast<const float2*>(&color_w[(size_t)cidx[cB] * EMB + 2 * m]);
        float2 sw = *reinterpret_cast<const float2*>(&size_w[(size_t)sidx[cB] * EMB + 2 * m]);
        b0 += cw.x + sw.x; b1 += cw.y + sw.y;
    }
    if (vA) {
        size_t o = (size_t)nA * 32 + m;
        totB[o] = pack2(a0, a1);
        y0[o] = pack2(a0 * dvA, a1 * dvA);
    }
    if (vB) {
        size_t o = (size_t)nB * 32 + m;
        totB[o] = pack2(b0, b1);
        y0[o] = pack2(b0 * dvB, b1 * dvB);
    }
}

// ================= bucketed CSR build =================
// pass 1: partition edges into NB col-range buckets (packed row<<9 | col&511)

__global__ __launch_bounds__(512) void partition_kernel(
        const int* __restrict__ row, const int* __restrict__ col,
        unsigned* __restrict__ bcursor, unsigned* __restrict__ bucketbuf,
        int E, int NB) {
    __shared__ unsigned h[NBMAX];
    __shared__ unsigned wbase[NBMAX];
    const int t = threadIdx.x;
    const long chunk = (long)blockIdx.x * CHUNK;

    for (int i = t; i < NB; i += 512) h[i] = 0u;
    __syncthreads();
    unsigned cc[2][4];
#pragma unroll
    for (int it = 0; it < 2; ++it) {
        long e = chunk + (long)it * 2048 + (long)t * 4;
        if (e + 3 < (long)E) {
            uint4 c4 = *reinterpret_cast<const uint4*>(&col[e]);
            cc[it][0] = c4.x; cc[it][1] = c4.y; cc[it][2] = c4.z; cc[it][3] = c4.w;
            atomicAdd(&h[c4.x >> 9], 1u); atomicAdd(&h[c4.y >> 9], 1u);
            atomicAdd(&h[c4.z >> 9], 1u); atomicAdd(&h[c4.w >> 9], 1u);
        } else {
#pragma unroll
            for (int k = 0; k < 4; ++k) {
                long ek = e + k;
                unsigned cv = (ek < (long)E) ? (unsigned)col[ek] : 0xffffffffu;
                cc[it][k] = cv;
                if (cv != 0xffffffffu) atomicAdd(&h[cv >> 9], 1u);
            }
        }
    }
    __syncthreads();
    for (int i = t; i < NB; i += 512) {
        unsigned c = h[i];
        wbase[i] = c ? atomicAdd(&bcursor[i], c) : 0u;
    }
    __syncthreads();
    for (int i = t; i < NB; i += 512) h[i] = 0u;
    __syncthreads();
#pragma unroll
    for (int it = 0; it < 2; ++it) {
        long e = chunk + (long)it * 2048 + (long)t * 4;
        if (e + 3 < (long)E) {
            uint4 r4 = *reinterpret_cast<const uint4*>(&row[e]);
            unsigned rs[4] = {r4.x, r4.y, r4.z, r4.w};
#pragma unroll
            for (int k = 0; k < 4; ++k) {
                unsigned cv = cc[it][k];
                unsigned b = cv >> 9;
                unsigned pos = wbase[b] + atomicAdd(&h[b], 1u);
                if (pos < BCAP)
                    bucketbuf[(size_t)b * BCAP + pos] = (rs[k] << 9) | (cv & 511u);
            }
        } else {
#pragma unroll
            for (int k = 0; k < 4; ++k) {
                long ek = e + k;
                unsigned cv = cc[it][k];
                if (cv != 0xffffffffu) {
                    unsigned b = cv >> 9;
                    unsigned pos = wbase[b] + atomicAdd(&h[b], 1u);
                    if (pos < BCAP)
                        bucketbuf[(size_t)b * BCAP + pos] =
                            (((unsigned)row[ek]) << 9) | (cv & 511u);
                }
            }
        }
    }
}

// pass 2: one 512-thread WG per bucket (1 node/thread). Packed edges are
// register-cached (cntb <= 16*512) across histogram->scatter. Produces meta
// (pad-8), dis, srcidx (pre-shifted + phantom pads), and longest-first
// in-bucket degree-sorted order[].

__global__ __launch_bounds__(512) void bucket_csr_kernel(
        const unsigned* __restrict__ bcursor,
        const unsigned* __restrict__ bucketbuf,
        uint4* __restrict__ meta,               // [N] {beg,end,dis_bits,0}
        float* __restrict__ dis, unsigned* __restrict__ srcidx,
        unsigned* __restrict__ order,           // [N] degree-sorted ids
        int N, int NB) {
    const int b = blockIdx.x;
    const int t = threadIdx.x;
    __shared__ unsigned hist[512];
    __shared__ unsigned ps[512];
    __shared__ unsigned cls[64];
    __shared__ unsigned clsB[64];

    const unsigned base = (unsigned)b * BSTRIDE;
    unsigned cntb = bcursor[b];
    if (cntb > BCAP) cntb = BCAP;

    hist[t] = 0u;
    if (t < 64) cls[t] = 0u;
    __syncthreads();
    const unsigned* buf = bucketbuf + (size_t)b * BCAP;
    unsigned rv[16];
#pragma unroll
    for (int it = 0; it < 16; ++it) {
        unsigned j = (unsigned)t + (unsigned)it * 512u;
        unsigned p = (j < cntb) ? buf[j] : 0xffffffffu;
        rv[it] = p;
        if (p != 0xffffffffu) atomicAdd(&hist[p & 511u], 1u);
    }
    __syncthreads();

    unsigned h0 = hist[t];
    unsigned c0p = (h0 + 7u) & ~7u;    // pad to multiple of 8
    ps[t] = c0p;
    __syncthreads();
    for (int off = 1; off < 512; off <<= 1) {
        unsigned y = (t >= off) ? ps[t - off] : 0u;
        __syncthreads();
        ps[t] += y;
        __syncthreads();
    }
    unsigned beg0 = base + ps[t] - c0p;

    int n0 = (b << 9) + t;
    unsigned c = 63u - min(c0p >> 3, 63u);   // inverted: longest-first
    unsigned lpos = 0;
    if (n0 < N) {
        float dv = h0 ? rsqrtf((float)h0) : 0.f;
        meta[n0] = make_uint4(beg0, beg0 + c0p, __float_as_uint(dv), 0u);
        dis[n0] = dv;
        lpos = atomicAdd(&cls[c], 1u);       // rank within class
        for (unsigned k = h0; k < c0p; ++k) srcidx[beg0 + k] = ((unsigned)N) << 5;
    }
    __syncthreads();
    if (t == 0) {   // exclusive scan of the 64 class counts
        unsigned run = 0;
        for (int i = 0; i < 64; ++i) { unsigned v = cls[i]; clsB[i] = run; run += v; }
    }
    __syncthreads();
    if (n0 < N) order[(b << 9) + clsB[c] + lpos] = (unsigned)n0;

    // scatter from registers via LDS cursors; writes stay in one bucket region
    hist[t] = beg0;
    __syncthreads();
#pragma unroll
    for (int it = 0; it < 16; ++it) {
        unsigned p = rv[it];
        if (p != 0xffffffffu) {
            unsigned pos = atomicAdd(&hist[p & 511u], 1u);
            srcidx[pos] = (p >> 9) << 5;   // u32 word offset of source row
        }
    }
}

// ================= propagation =================
// TWO nodes per wave (degree-sorted, longest-first), 16-edge unrolled main
// loop with two accumulator banks + one 8-edge tail (lists pad-8). totB read
// hoisted. mode 0: RMW bf16 totB + store ynext; mode 1: f32 out*(0.25) fused.

__global__ __launch_bounds__(256) void gather_propagate_kernel(
        const unsigned* __restrict__ order, const uint4* __restrict__ meta,
        const unsigned* __restrict__ src,   // [(N+1)*32]
        const unsigned* __restrict__ srcidx,
        unsigned* __restrict__ ynext,       // [(N+1)*32]
        unsigned* __restrict__ totB,        // [N*32] bf16x2
        float4* __restrict__ outF,          // [N*16] f32 (mode 1)
        int N, int mode) {
    int lane = threadIdx.x & 63;
    int slot = blockIdx.x * 8 + ((threadIdx.x >> 6) << 1) + (lane >> 5);
    bool active = slot < N;
    int n = active ? (int)order[slot] : 0;
    uint4 md = active ? meta[n] : make_uint4(0u, 0u, 0u, 0u);
    unsigned beg = md.x, endp = md.y;
    float dn = __uint_as_float(md.z);
    unsigned q = (unsigned)((lane >> 4) & 1);
    unsigned m2 = (unsigned)(lane & 15) * 2u;
    size_t o = (size_t)n * 32 + m2;
    uint2 tv = *reinterpret_cast<const uint2*>(&totB[o]);   // hoisted RMW-read
    float s0 = 0.f, s1 = 0.f, s2 = 0.f, s3 = 0.f;
    float t0 = 0.f, t1 = 0.f, t2 = 0.f, t3 = 0.f;
    unsigned j = beg;
    for (; j + 16 <= endp; j += 16) {   // 16 edges/node/iter, 2 chains
        uint4 iv0 = *reinterpret_cast<const uint4*>(&srcidx[j + 4u * q]);
        uint4 iv1 = *reinterpret_cast<const uint4*>(&srcidx[j + 8u + 4u * q]);
        uint2 ua = *reinterpret_cast<const uint2*>(&src[iv0.x + m2]);
        uint2 ub = *reinterpret_cast<const uint2*>(&src[iv0.y + m2]);
        uint2 uc = *reinterpret_cast<const uint2*>(&src[iv0.z + m2]);
        uint2 ud = *reinterpret_cast<const uint2*>(&src[iv0.w + m2]);
        uint2 ue = *reinterpret_cast<const uint2*>(&src[iv1.x + m2]);
        uint2 uf = *reinterpret_cast<const uint2*>(&src[iv1.y + m2]);
        uint2 ug = *reinterpret_cast<const uint2*>(&src[iv1.z + m2]);
        uint2 uh = *reinterpret_cast<const uint2*>(&src[iv1.w + m2]);
        s0 += (bflo(ua.x) + bflo(ub.x)) + (bflo(uc.x) + bflo(ud.x));
        s1 += (bfhi(ua.x) + bfhi(ub.x)) + (bfhi(uc.x) + bfhi(ud.x));
        s2 += (bflo(ua.y) + bflo(ub.y)) + (bflo(uc.y) + bflo(ud.y));
        s3 += (bfhi(ua.y) + bfhi(ub.y)) + (bfhi(uc.y) + bfhi(ud.y));
        t0 += (bflo(ue.x) + bflo(uf.x)) + (bflo(ug.x) + bflo(uh.x));
        t1 += (bfhi(ue.x) + bfhi(uf.x)) + (bfhi(ug.x) + bfhi(uh.x));
        t2 += (bflo(ue.y) + bflo(uf.y)) + (bflo(ug.y) + bflo(uh.y));
        t3 += (bfhi(ue.y) + bfhi(uf.y)) + (bfhi(ug.y) + bfhi(uh.y));
    }
    if (j < endp) {   // exactly one 8-edge tail (pad-8 lists)
        uint4 iv = *reinterpret_cast<const uint4*>(&srcidx[j + 4u * q]);
        uint2 ua = *reinterpret_cast<const uint2*>(&src[iv.x + m2]);
        uint2 ub = *reinterpret_cast<const uint2*>(&src[iv.y + m2]);
        uint2 uc = *reinterpret_cast<const uint2*>(&src[iv.z + m2]);
        uint2 ud = *reinterpret_cast<const uint2*>(&src[iv.w + m2]);
        s0 += (bflo(ua.x) + bflo(ub.x)) + (bflo(uc.x) + bflo(ud.x));
        s1 += (bfhi(ua.x) + bfhi(ub.x)) + (bfhi(uc.x) + bfhi(ud.x));
        s2 += (bflo(ua.y) + bflo(ub.y)) + (bflo(uc.y) + bflo(ud.y));
        s3 += (bfhi(ua.y) + bfhi(ub.y)) + (bfhi(uc.y) + bfhi(ud.y));
    }
    s0 += t0; s1 += t1; s2 += t2; s3 += t3;
    // combine the two q-groups within each half (xor 16 stays inside the half)
    s0 += __shfl_xor(s0, 16);
    s1 += __shfl_xor(s1, 16);
    s2 += __shfl_xor(s2, 16);
    s3 += __shfl_xor(s3, 16);
    if (active && (lane & 31) < 16) {
        float a0 = dn * s0, a1 = dn * s1, a2 = dn * s2, a3 = dn * s3;
        float b0 = bflo(tv.x) + a0, b1 = bfhi(tv.x) + a1;
        float b2 = bflo(tv.y) + a2, b3 = bfhi(tv.y) + a3;
        if (mode == 0) {
            uint2 nv;
            nv.x = pack2(b0, b1);
            nv.y = pack2(b2, b3);
            *reinterpret_cast<uint2*>(&totB[o]) = nv;
            uint2 pk;
            pk.x = pack2(dn * a0, dn * a1);
            pk.y = pack2(dn * a2, dn * a3);
            *reinterpret_cast<uint2*>(&ynext[(size_t)n * 32 + m2]) = pk;
        } else {
            outF[(size_t)n * 16 + (m2 >> 1)] =
                make_float4(b0 * 0.25f, b1 * 0.25f, b2 * 0.25f, b3 * 0.25f);
        }
    }
}

// ================= launch =================

extern "C" void kernel_launch(void* const* d_in, const int* in_sizes, int n_in,
                              void* d_out, int out_size, void* d_ws, size_t ws_size,
                              hipStream_t stream) {
    const int*   edge       = (const int*)d_in[0];
    const float* user_feat  = (const float*)d_in[1];
    const int*   cidx       = (const int*)d_in[2];
    const int*   sidx       = (const int*)d_in[3];
    const float* item_feat  = (const float*)d_in[4];
    const float* user_emb_w = (const float*)d_in[5];
    const float* item_emb_w = (const float*)d_in[6];
    const float* uWn        = (const float*)d_in[7];
    const float* ubn        = (const float*)d_in[8];
    const float* uWv        = (const float*)d_in[9];
    const float* ubv        = (const float*)d_in[10];
    const float* color_w    = (const float*)d_in[11];
    const float* size_w     = (const float*)d_in[12];
    const float* iWn        = (const float*)d_in[13];
    const float* ibn        = (const float*)d_in[14];
    const float* iWv        = (const float*)d_in[15];
    const float* ibv        = (const float*)d_in[16];

    const int E = in_sizes[0] / 2;
    const int U = in_sizes[5] / EMB;
    const int I = in_sizes[6] / EMB;
    const int N = U + I;
    const int NB = (N + 511) >> 9;     // 293 buckets

    const int* row = edge;
    const int* col = edge + E;

    // workspace layout (u32 units)
    unsigned short* yA      = (unsigned short*)d_ws;          // [(N+1)*64] bf16
    unsigned short* yB      = yA + (size_t)(N + 1) * EMB;     // [(N+1)*64] bf16
    unsigned*       bucketbuf = (unsigned*)yB;                // [NB*BCAP] aliases yB
                                                              // (dummy row at word
                                                              // N*32=4.8M > 2.4M cap
                                                              // -> no overlap)
    unsigned short* totB    = yB + (size_t)(N + 1) * EMB;     // [N*64] bf16 running sum
    unsigned*       srcidx  = (unsigned*)(totB + (size_t)N * EMB);      // [NB*BSTRIDE]
    uint4*          meta    = (uint4*)(srcidx + (size_t)NB * BSTRIDE);  // [N]
    float*          dis     = (float*)(meta + N);             // [N]
    unsigned*       bcursor = (unsigned*)(dis + N);           // [NB]
    unsigned*       order   = bcursor + ((NB + 1) & ~1);      // [N] (8B-aligned)
    float*          wbuf    = (float*)(order + ((N + 1) & ~1)); // [WSZ] (8B-aligned)

    const int TB = 256;

    // 1. init (bcursor + phantom rows) + weight prep, then CSR build
    init_kernel<<<(NB + TB - 1) / TB, TB, 0, stream>>>(
        bcursor, NB,
        (unsigned*)(yA + (size_t)N * EMB), (unsigned*)(yB + (size_t)N * EMB));
    prep_weights_kernel<<<(WSZ + TB - 1) / TB, TB, 0, stream>>>(
        uWn, ubn, uWv, ubv, iWn, ibn, iWv, ibv, wbuf);
    const int gP = (E + CHUNK - 1) / CHUNK;
    partition_kernel<<<gP, 512, 0, stream>>>(row, col, bcursor, bucketbuf, E, NB);
    bucket_csr_kernel<<<NB, 512, 0, stream>>>(bcursor, bucketbuf, meta, dis,
                                              srcidx, order, N, NB);

    // 2. fuse features: totB = bf16(x), yA = bf16(dis*x)  (16 nodes/block)
    fuse_kernel<<<(N + 15) / 16, TB, 0, stream>>>(
        user_feat, cidx, sidx, user_emb_w, color_w, size_w,
        item_feat, item_emb_w, wbuf, dis,
        (unsigned*)totB, (unsigned*)yA, U, N);

    // 3. three propagation layers; finalize fused into layer 3 (mode 1)
    const int gG = (N + 7) / 8;   // 8 degree-matched nodes per block (2/wave)
    gather_propagate_kernel<<<gG, TB, 0, stream>>>(order, meta,
                                                   (const unsigned*)yA, srcidx,
                                                   (unsigned*)yB, (unsigned*)totB,
                                                   (float4*)d_out, N, 0);
    gather_propagate_kernel<<<gG, TB, 0, stream>>>(order, meta,
                                                   (const unsigned*)yB, srcidx,
                                                   (unsigned*)yA, (unsigned*)totB,
                                                   (float4*)d_out, N, 0);
    gather_propagate_kernel<<<gG, TB, 0, stream>>>(order, meta,
                                                   (const unsigned*)yA, srcidx,
                                                   (unsigned*)yB, (unsigned*)totB,
                                                   (float4*)d_out, N, 1);

    (void)n_in; (void)out_size; (void)ws_size;
}